// Round 12
// baseline (192.693 us; speedup 1.0000x reference)
//
#include <hip/hip_runtime.h>
#include <hip/hip_fp16.h>

// GCN 2-layer forward. CSR via bucket sort; aggregations channel-split into
// two passes (32 channels each) so the gather table (3.2 MB/pass) fits the
// 4 MB per-XCD L2 -> random gathers become L2 hits.
//  K1 : gemm1 (g1 = x@W1, fp16, unscaled) || edge histogram
//  K2a-d: scan rows / scan totals / bucket scatter / CSR finalize
//  K3a,b: aggregate1 pass0/1 -> Bh = relu(dinv*(sum dinv[s]*g1[s]) + b1), fp16
//  K4 : gemm2 (g2 = (Bh@W2)*dinv, fp16)
//  K5a,b: aggregate2 pass0/1 -> d_out = dinv*(sum g2[s]) + b2, f32

#define C_HID 64

static inline size_t alignup(size_t x) { return (x + 255) & ~(size_t)255; }

typedef __attribute__((address_space(3))) unsigned int lds_uint;
typedef __attribute__((address_space(1))) const unsigned int glob_uint;

// ---- block-wide inclusive scan over 256 threads ----
__device__ __forceinline__ int blockScanIncl256(int v, int* wsum) {
    const int lane = threadIdx.x & 63, wav = threadIdx.x >> 6;
    int s = v;
#pragma unroll
    for (int off = 1; off < 64; off <<= 1) {
        int t = __shfl_up(s, off);
        if (lane >= off) s += t;
    }
    if (lane == 63) wsum[wav] = s;
    __syncthreads();
    if (wav == 0 && lane < 4) {
        int ws = wsum[lane];
#pragma unroll
        for (int off = 1; off < 4; off <<= 1) {
            int t = __shfl_up(ws, off);
            if (lane >= off) ws += t;
        }
        wsum[lane] = ws;
    }
    __syncthreads();
    return (wav ? wsum[wav - 1] : 0) + s;
}

// ================= K1: gemm1 || hist =================
template <int K>
__global__ __launch_bounds__(256) void gemm1_hist_kernel(
    const float* __restrict__ X, const float* __restrict__ W,
    const int* __restrict__ dst, __half* __restrict__ outh,
    int* __restrict__ S, int n, int E, int ePer, int nb) {
    constexpr int KP = K + 4;
    __shared__ float Xs[64 * KP];
    __shared__ float Ws[K * 64];
    __shared__ int h[256];
    const int t = threadIdx.x;
    const int lane = t & 63;
    const int wav = t >> 6;

    if ((int)blockIdx.x < nb) {
        h[t] = 0;
        __syncthreads();
        int beg = blockIdx.x * ePer, end = min(E, beg + ePer);
        for (int e = beg + t; e < end; e += 256)
            atomicAdd(&h[dst[e] >> 8], 1);
        __syncthreads();
        for (int b = t; b < nb; b += 256)
            S[(size_t)b * nb + blockIdx.x] = h[b];
        return;
    }

    const int row0 = ((int)blockIdx.x - nb) * 64;
    {
        const char* gb = (const char*)W;
        char* lb = (char*)Ws;
        for (int off = wav * 1024; off < K * 64 * 4; off += 4096)
            __builtin_amdgcn_global_load_lds((glob_uint*)(gb + off + lane * 16),
                                             (lds_uint*)(lb + off), 16, 0, 0);
    }
    if (row0 + 64 <= n) {
        const float4* g4 = (const float4*)(X + (size_t)row0 * K);
        for (int i = t; i < 64 * (K / 4); i += 256) {
            float4 v = g4[i];
            int r = i / (K / 4), k0 = (i % (K / 4)) * 4;
            *(float4*)&Xs[r * KP + k0] = v;
        }
    } else {
        for (int i = t; i < 64 * K; i += 256) {
            int r = i / K, k = i % K;
            Xs[r * KP + k] = (row0 + r < n) ? X[(size_t)(row0 + r) * K + k] : 0.0f;
        }
    }
    __syncthreads();

    const int tx = t & 15;
    const int ty = t >> 4;
    float acc[4][4] = {{0.f}};
#pragma unroll 2
    for (int k0 = 0; k0 < K; k0 += 4) {
        float4 a0 = *(const float4*)&Xs[(4 * ty + 0) * KP + k0];
        float4 a1 = *(const float4*)&Xs[(4 * ty + 1) * KP + k0];
        float4 a2 = *(const float4*)&Xs[(4 * ty + 2) * KP + k0];
        float4 a3 = *(const float4*)&Xs[(4 * ty + 3) * KP + k0];
        float4 b0 = *(const float4*)&Ws[(k0 + 0) * 64 + 4 * tx];
        float4 b1 = *(const float4*)&Ws[(k0 + 1) * 64 + 4 * tx];
        float4 b2 = *(const float4*)&Ws[(k0 + 2) * 64 + 4 * tx];
        float4 b3 = *(const float4*)&Ws[(k0 + 3) * 64 + 4 * tx];
        const float* ap[4] = {(const float*)&a0, (const float*)&a1,
                              (const float*)&a2, (const float*)&a3};
        const float* bp[4] = {(const float*)&b0, (const float*)&b1,
                              (const float*)&b2, (const float*)&b3};
#pragma unroll
        for (int r = 0; r < 4; ++r)
#pragma unroll
            for (int kk = 0; kk < 4; ++kk) {
                float av = ap[r][kk];
#pragma unroll
                for (int c = 0; c < 4; ++c)
                    acc[r][c] = fmaf(av, bp[kk][c], acc[r][c]);
            }
    }
#pragma unroll
    for (int r = 0; r < 4; ++r) {
        int row = row0 + 4 * ty + r;
        if (row < n) {
            __half2 p01 = __floats2half2_rn(acc[r][0], acc[r][1]);
            __half2 p23 = __floats2half2_rn(acc[r][2], acc[r][3]);
            float2 st;
            ((__half2*)&st)[0] = p01;
            ((__half2*)&st)[1] = p23;
            *(float2*)&outh[(size_t)row * 64 + 4 * tx] = st;
        }
    }
}

// ================= K2a: exclusive scan of each bucket-row of S; T[b] = row total ====
__global__ __launch_bounds__(256) void scan_rows_kernel(
    int* __restrict__ S, int* __restrict__ T, int nb) {
    __shared__ int wsum[4];
    const int b = blockIdx.x, t = threadIdx.x;
    int v = (t < nb) ? S[(size_t)b * nb + t] : 0;
    int incl = blockScanIncl256(v, wsum);
    if (t < nb) S[(size_t)b * nb + t] = incl - v;
    if (t == 0) T[b] = wsum[3];
}

// ================= K2b: exclusive scan of T (one block); T[nb] = E ================
__global__ __launch_bounds__(256) void scan_T_kernel(int* __restrict__ T, int nb) {
    __shared__ int wsum[4];
    const int t = threadIdx.x;
    int v = (t < nb) ? T[t] : 0;
    int incl = blockScanIncl256(v, wsum);
    if (t < nb) T[t] = incl - v;
    if (t == nb - 1) T[nb] = incl;   // total
}

// ================= K2c: bucket scatter =================
__global__ __launch_bounds__(256) void scatter_kernel(
    const int* __restrict__ src, const int* __restrict__ dst, int E, int ePer,
    const int* __restrict__ S, const int* __restrict__ T,
    unsigned* __restrict__ ebuf, int nb) {
    __shared__ int arr[256];
    const int b = blockIdx.x, t = threadIdx.x;
    if (t < nb) arr[t] = S[(size_t)t * nb + b] + T[t];
    __syncthreads();
    int beg = b * ePer, end = min(E, beg + ePer);
    for (int e = beg + t; e < end; e += 256) {
        int d = dst[e];
        int s = src[e];
        int pos = atomicAdd(&arr[d >> 8], 1);            // LDS atomic
        ebuf[pos] = ((unsigned)s << 8) | (unsigned)(d & 255);
    }
}

// ================= K2d: per-bucket CSR finalize =================
__global__ __launch_bounds__(256) void build_kernel(
    const unsigned* __restrict__ ebuf, const int* __restrict__ T,
    int* __restrict__ row_ptr, float* __restrict__ dinv,
    int* __restrict__ esrc, int n, int nb) {
    __shared__ int arr[256];
    __shared__ int wsum[4];
    const int b = blockIdx.x, t = threadIdx.x;
    const int node0 = b << 8;
    const int ebeg = T[b];
    const int eend = T[b + 1];

    arr[t] = 0;
    __syncthreads();
    for (int e = ebeg + t; e < eend; e += 256)
        atomicAdd(&arr[ebuf[e] & 255], 1);
    __syncthreads();
    int deg = arr[t];
    int incl = blockScanIncl256(deg, wsum);
    int excl = incl - deg;
    __syncthreads();
    arr[t] = ebeg + excl;   // cursor
    int v = node0 + t;
    if (v < n) {
        row_ptr[v + 1] = ebeg + incl;
        dinv[v] = rsqrtf(1.0f + (float)deg);
        if (v == 0) row_ptr[0] = 0;
    }
    __syncthreads();
    for (int e = ebeg + t; e < eend; e += 256) {
        unsigned p = ebuf[e];
        int pos = atomicAdd(&arr[p & 255], 1);           // LDS atomic
        esrc[pos] = (int)(p >> 8);
    }
}

// ================= K3: aggregate1, one channel-half per launch =================
// 8-lane group per node; lane c8 owns 4 channels (8B fp16) of this pass's half.
// acc = dinv[v]*g1[v] + sum dinv[s]*g1[s]; Bh = relu(dinv[v]*acc + b1) fp16.
__global__ __launch_bounds__(256) void agg1_half_kernel(
    const __half* __restrict__ g1, const int* __restrict__ row_ptr,
    const int* __restrict__ esrc, const float* __restrict__ dinv,
    const float* __restrict__ b1, __half* __restrict__ Bh, int n, int pass) {
    const int v = blockIdx.x * 32 + (threadIdx.x >> 3);
    if (v >= n) return;
    const int c8 = threadIdx.x & 7;
    const int cidx = pass * 8 + c8;               // 8B chunk index within row (16 total)
    const float2* __restrict__ hs2 = (const float2*)g1;

    float dv = dinv[v];
    float a0, a1, a2, a3;
    {
        float2 raw = hs2[(size_t)v * 16 + cidx];
        const __half2* hp = (const __half2*)&raw;
        float2 f0 = __half22float2(hp[0]), f1 = __half22float2(hp[1]);
        a0 = f0.x * dv; a1 = f0.y * dv; a2 = f1.x * dv; a3 = f1.y * dv;
    }
    const int beg = row_ptr[v], end = row_ptr[v + 1];
    int j = beg;
    for (; j + 4 <= end; j += 4) {
        int s0 = esrc[j], s1 = esrc[j + 1], s2 = esrc[j + 2], s3 = esrc[j + 3];
        float d0 = dinv[s0], d1 = dinv[s1], d2 = dinv[s2], d3 = dinv[s3];
        float2 r0 = hs2[(size_t)s0 * 16 + cidx];
        float2 r1 = hs2[(size_t)s1 * 16 + cidx];
        float2 r2 = hs2[(size_t)s2 * 16 + cidx];
        float2 r3 = hs2[(size_t)s3 * 16 + cidx];
        const __half2* h0 = (const __half2*)&r0;
        const __half2* h1 = (const __half2*)&r1;
        const __half2* h2 = (const __half2*)&r2;
        const __half2* h3 = (const __half2*)&r3;
        float2 f;
        f = __half22float2(h0[0]); a0 = fmaf(f.x, d0, a0); a1 = fmaf(f.y, d0, a1);
        f = __half22float2(h0[1]); a2 = fmaf(f.x, d0, a2); a3 = fmaf(f.y, d0, a3);
        f = __half22float2(h1[0]); a0 = fmaf(f.x, d1, a0); a1 = fmaf(f.y, d1, a1);
        f = __half22float2(h1[1]); a2 = fmaf(f.x, d1, a2); a3 = fmaf(f.y, d1, a3);
        f = __half22float2(h2[0]); a0 = fmaf(f.x, d2, a0); a1 = fmaf(f.y, d2, a1);
        f = __half22float2(h2[1]); a2 = fmaf(f.x, d2, a2); a3 = fmaf(f.y, d2, a3);
        f = __half22float2(h3[0]); a0 = fmaf(f.x, d3, a0); a1 = fmaf(f.y, d3, a1);
        f = __half22float2(h3[1]); a2 = fmaf(f.x, d3, a2); a3 = fmaf(f.y, d3, a3);
    }
    for (; j < end; ++j) {
        int s0 = esrc[j];
        float d0 = dinv[s0];
        float2 r0 = hs2[(size_t)s0 * 16 + cidx];
        const __half2* h0 = (const __half2*)&r0;
        float2 f;
        f = __half22float2(h0[0]); a0 = fmaf(f.x, d0, a0); a1 = fmaf(f.y, d0, a1);
        f = __half22float2(h0[1]); a2 = fmaf(f.x, d0, a2); a3 = fmaf(f.y, d0, a3);
    }
    float4 b = *(const float4*)(b1 + cidx * 4);
    float r0 = fmaxf(fmaf(a0, dv, b.x), 0.f);
    float r1 = fmaxf(fmaf(a1, dv, b.y), 0.f);
    float r2 = fmaxf(fmaf(a2, dv, b.z), 0.f);
    float r3 = fmaxf(fmaf(a3, dv, b.w), 0.f);
    float2 st;
    ((__half2*)&st)[0] = __floats2half2_rn(r0, r1);
    ((__half2*)&st)[1] = __floats2half2_rn(r2, r3);
    ((float2*)Bh)[(size_t)v * 16 + cidx] = st;
}

// ================= K5: aggregate2, one channel-half per launch =================
// g2 rows pre-scaled by dinv[src]; out = dinv[v]*(sum) + b2, f32.
__global__ __launch_bounds__(256) void agg2_half_kernel(
    const __half* __restrict__ g2, const int* __restrict__ row_ptr,
    const int* __restrict__ esrc, const float* __restrict__ dinv,
    const float* __restrict__ b2, float* __restrict__ out, int n, int pass) {
    const int v = blockIdx.x * 32 + (threadIdx.x >> 3);
    if (v >= n) return;
    const int c8 = threadIdx.x & 7;
    const int cidx = pass * 8 + c8;
    const float2* __restrict__ hs2 = (const float2*)g2;

    float a0, a1, a2, a3;
    {
        float2 raw = hs2[(size_t)v * 16 + cidx];
        const __half2* hp = (const __half2*)&raw;
        float2 f0 = __half22float2(hp[0]), f1 = __half22float2(hp[1]);
        a0 = f0.x; a1 = f0.y; a2 = f1.x; a3 = f1.y;
    }
    const int beg = row_ptr[v], end = row_ptr[v + 1];
    int j = beg;
    for (; j + 4 <= end; j += 4) {
        int s0 = esrc[j], s1 = esrc[j + 1], s2 = esrc[j + 2], s3 = esrc[j + 3];
        float2 r0 = hs2[(size_t)s0 * 16 + cidx];
        float2 r1 = hs2[(size_t)s1 * 16 + cidx];
        float2 r2 = hs2[(size_t)s2 * 16 + cidx];
        float2 r3 = hs2[(size_t)s3 * 16 + cidx];
        const __half2* h0 = (const __half2*)&r0;
        const __half2* h1 = (const __half2*)&r1;
        const __half2* h2 = (const __half2*)&r2;
        const __half2* h3 = (const __half2*)&r3;
        float2 f0 = __half22float2(h0[0]), g0 = __half22float2(h0[1]);
        float2 f1 = __half22float2(h1[0]), g1v = __half22float2(h1[1]);
        float2 f2 = __half22float2(h2[0]), g2v = __half22float2(h2[1]);
        float2 f3 = __half22float2(h3[0]), g3 = __half22float2(h3[1]);
        a0 += (f0.x + f1.x) + (f2.x + f3.x);
        a1 += (f0.y + f1.y) + (f2.y + f3.y);
        a2 += (g0.x + g1v.x) + (g2v.x + g3.x);
        a3 += (g0.y + g1v.y) + (g2v.y + g3.y);
    }
    for (; j < end; ++j) {
        int s0 = esrc[j];
        float2 r0 = hs2[(size_t)s0 * 16 + cidx];
        const __half2* h0 = (const __half2*)&r0;
        float2 f = __half22float2(h0[0]), g = __half22float2(h0[1]);
        a0 += f.x; a1 += f.y; a2 += g.x; a3 += g.y;
    }
    float dv = dinv[v];
    float4 b = *(const float4*)(b2 + cidx * 4);
    float4 o;
    o.x = fmaf(a0, dv, b.x);
    o.y = fmaf(a1, dv, b.y);
    o.z = fmaf(a2, dv, b.z);
    o.w = fmaf(a3, dv, b.w);
    *(float4*)(out + (size_t)v * 64 + cidx * 4) = o;
}

// ================= K4: gemm2, fp16 input: g2 = (Bh @ W2) * dinv, fp16 out =======
__global__ __launch_bounds__(256) void gemm2_h_kernel(
    const __half* __restrict__ Xh, const float* __restrict__ W,
    const float* __restrict__ dinv, __half* __restrict__ outh, int n) {
    constexpr int K = 64, KP = 68;
    __shared__ float Xs[64 * KP];
    __shared__ float Ws[K * 64];
    const int t = threadIdx.x;
    const int lane = t & 63;
    const int wav = t >> 6;
    const int row0 = blockIdx.x * 64;

    {
        const char* gb = (const char*)W;
        char* lb = (char*)Ws;
        for (int off = wav * 1024; off < K * 64 * 4; off += 4096)
            __builtin_amdgcn_global_load_lds((glob_uint*)(gb + off + lane * 16),
                                             (lds_uint*)(lb + off), 16, 0, 0);
    }
    if (row0 + 64 <= n) {
        const float2* g2p = (const float2*)(Xh + (size_t)row0 * 64);
        for (int i = t; i < 64 * 16; i += 256) {
            float2 raw = g2p[i];
            const __half2* hp = (const __half2*)&raw;
            float2 f0 = __half22float2(hp[0]), f1 = __half22float2(hp[1]);
            int r = i >> 4, c4 = (i & 15) * 4;
            *(float4*)&Xs[r * KP + c4] = make_float4(f0.x, f0.y, f1.x, f1.y);
        }
    } else {
        for (int i = t; i < 64 * K; i += 256) {
            int r = i / K, k = i % K;
            Xs[r * KP + k] = (row0 + r < n) ? (float)Xh[(size_t)(row0 + r) * K + k] : 0.0f;
        }
    }
    __syncthreads();

    const int tx = t & 15;
    const int ty = t >> 4;
    float acc[4][4] = {{0.f}};
#pragma unroll 2
    for (int k0 = 0; k0 < K; k0 += 4) {
        float4 a0 = *(const float4*)&Xs[(4 * ty + 0) * KP + k0];
        float4 a1 = *(const float4*)&Xs[(4 * ty + 1) * KP + k0];
        float4 a2 = *(const float4*)&Xs[(4 * ty + 2) * KP + k0];
        float4 a3 = *(const float4*)&Xs[(4 * ty + 3) * KP + k0];
        float4 b0 = *(const float4*)&Ws[(k0 + 0) * 64 + 4 * tx];
        float4 b1 = *(const float4*)&Ws[(k0 + 1) * 64 + 4 * tx];
        float4 b2 = *(const float4*)&Ws[(k0 + 2) * 64 + 4 * tx];
        float4 b3 = *(const float4*)&Ws[(k0 + 3) * 64 + 4 * tx];
        const float* ap[4] = {(const float*)&a0, (const float*)&a1,
                              (const float*)&a2, (const float*)&a3};
        const float* bp[4] = {(const float*)&b0, (const float*)&b1,
                              (const float*)&b2, (const float*)&b3};
#pragma unroll
        for (int r = 0; r < 4; ++r)
#pragma unroll
            for (int kk = 0; kk < 4; ++kk) {
                float av = ap[r][kk];
#pragma unroll
                for (int c = 0; c < 4; ++c)
                    acc[r][c] = fmaf(av, bp[kk][c], acc[r][c]);
            }
    }
#pragma unroll
    for (int r = 0; r < 4; ++r) {
        int row = row0 + 4 * ty + r;
        if (row < n) {
            float dv = dinv[row];
            __half2 p01 = __floats2half2_rn(acc[r][0] * dv, acc[r][1] * dv);
            __half2 p23 = __floats2half2_rn(acc[r][2] * dv, acc[r][3] * dv);
            float2 st;
            ((__half2*)&st)[0] = p01;
            ((__half2*)&st)[1] = p23;
            *(float2*)&outh[(size_t)row * 64 + 4 * tx] = st;
        }
    }
}

extern "C" void kernel_launch(void* const* d_in, const int* in_sizes, int n_in,
                              void* d_out, int out_size, void* d_ws, size_t ws_size,
                              hipStream_t stream) {
    const float* x  = (const float*)d_in[0];
    const int*   ei = (const int*)d_in[1];
    const float* W1 = (const float*)d_in[2];
    const float* b1 = (const float*)d_in[3];
    const float* W2 = (const float*)d_in[4];
    const float* b2 = (const float*)d_in[5];
    float* out = (float*)d_out;

    const int C_IN = 128;
    const int n = in_sizes[0] / C_IN;   // 50000 (<= 65536 required)
    const int E = in_sizes[1] / 2;      // 800000
    const int* src = ei;
    const int* dst = ei + E;

    const int nb = (n + 255) >> 8;              // 196 buckets (<= 256)
    const int ngb = (n + 63) / 64;              // gemm tile blocks
    const int nab = (n + 31) / 32;              // aggregate blocks per pass
    const int ePer = (E + nb - 1) / nb;         // edges per hist/scatter chunk

    // Workspace: dinv | g1 | Bh | g2 | row_ptr | S | T | ebuf | esrc
    char* w = (char*)d_ws;
    float*    dinv    = (float*)w;    w += alignup((size_t)n * sizeof(float));
    __half*   g1      = (__half*)w;   w += alignup((size_t)n * C_HID * sizeof(__half));
    __half*   Bh      = (__half*)w;   w += alignup((size_t)n * C_HID * sizeof(__half));
    __half*   g2      = (__half*)w;   w += alignup((size_t)n * C_HID * sizeof(__half));
    int*      row_ptr = (int*)w;      w += alignup((size_t)(n + 1) * sizeof(int));
    int*      S       = (int*)w;      w += alignup((size_t)nb * nb * sizeof(int));
    int*      T       = (int*)w;      w += alignup((size_t)(nb + 1) * sizeof(int));
    unsigned* ebuf    = (unsigned*)w; w += alignup((size_t)E * sizeof(unsigned));
    int*      esrc    = (int*)w;

    // K1: gemm1 || hist
    gemm1_hist_kernel<128><<<nb + ngb, 256, 0, stream>>>(
        x, W1, dst, g1, S, n, E, ePer, nb);

    // K2: CSR build
    scan_rows_kernel<<<nb, 256, 0, stream>>>(S, T, nb);
    scan_T_kernel<<<1, 256, 0, stream>>>(T, nb);
    scatter_kernel<<<nb, 256, 0, stream>>>(src, dst, E, ePer, S, T, ebuf, nb);
    build_kernel<<<nb, 256, 0, stream>>>(ebuf, T, row_ptr, dinv, esrc, n, nb);

    // K3: aggregate1, two channel-half passes (3.2 MB table per pass -> L2-resident)
    agg1_half_kernel<<<nab, 256, 0, stream>>>(g1, row_ptr, esrc, dinv, b1, Bh, n, 0);
    agg1_half_kernel<<<nab, 256, 0, stream>>>(g1, row_ptr, esrc, dinv, b1, Bh, n, 1);

    // K4: gemm2
    gemm2_h_kernel<<<ngb, 256, 0, stream>>>(Bh, W2, dinv, g2, n);

    // K5: aggregate2, two channel-half passes
    agg2_half_kernel<<<nab, 256, 0, stream>>>(g2, row_ptr, esrc, dinv, b2, out, n, 0);
    agg2_half_kernel<<<nab, 256, 0, stream>>>(g2, row_ptr, esrc, dinv, b2, out, n, 1);
}

// Round 13
// 161.219 us; speedup vs baseline: 1.1952x; 1.1952x over previous
//
#include <hip/hip_runtime.h>
#include <hip/hip_fp16.h>

// GCN 2-layer forward (round-11 structure, -1 launch, deeper agg MLP):
//  K1 : gemm1 (g1 = x@W1, fp16, unscaled) || edge histogram
//  K2a: per-bucket row scan of S -> T totals
//  K2b: bucket scatter (in-block redundant T scan)
//  K2c: per-bucket CSR finalize (in-block redundant T scan)
//  K3 : aggregate1 (acc += dinv[s]*g1[s]) -> relu -> gemm2 from LDS -> g2 fp16 (pre-scaled)
//  K4 : aggregate2 -> d_out

#define C_HID 64

static inline size_t alignup(size_t x) { return (x + 255) & ~(size_t)255; }

typedef __attribute__((address_space(3))) unsigned int lds_uint;
typedef __attribute__((address_space(1))) const unsigned int glob_uint;

// ---- block-wide inclusive scan over 256 threads ----
__device__ __forceinline__ int blockScanIncl256(int v, int* wsum) {
    const int lane = threadIdx.x & 63, wav = threadIdx.x >> 6;
    int s = v;
#pragma unroll
    for (int off = 1; off < 64; off <<= 1) {
        int t = __shfl_up(s, off);
        if (lane >= off) s += t;
    }
    if (lane == 63) wsum[wav] = s;
    __syncthreads();
    if (wav == 0 && lane < 4) {
        int ws = wsum[lane];
#pragma unroll
        for (int off = 1; off < 4; off <<= 1) {
            int t = __shfl_up(ws, off);
            if (lane >= off) ws += t;
        }
        wsum[lane] = ws;
    }
    __syncthreads();
    return (wav ? wsum[wav - 1] : 0) + s;
}

// ================= K1: gemm1 || hist =================
template <int K>
__global__ __launch_bounds__(256) void gemm1_hist_kernel(
    const float* __restrict__ X, const float* __restrict__ W,
    const int* __restrict__ dst, __half* __restrict__ outh,
    int* __restrict__ S, int n, int E, int ePer, int nb) {
    constexpr int KP = K + 4;
    __shared__ float Xs[64 * KP];
    __shared__ float Ws[K * 64];
    __shared__ int h[256];
    const int t = threadIdx.x;
    const int lane = t & 63;
    const int wav = t >> 6;

    if ((int)blockIdx.x < nb) {
        h[t] = 0;
        __syncthreads();
        int beg = blockIdx.x * ePer, end = min(E, beg + ePer);
        for (int e = beg + t; e < end; e += 256)
            atomicAdd(&h[dst[e] >> 8], 1);
        __syncthreads();
        for (int b = t; b < nb; b += 256)
            S[(size_t)b * nb + blockIdx.x] = h[b];
        return;
    }

    const int row0 = ((int)blockIdx.x - nb) * 64;
    {
        const char* gb = (const char*)W;
        char* lb = (char*)Ws;
        for (int off = wav * 1024; off < K * 64 * 4; off += 4096)
            __builtin_amdgcn_global_load_lds((glob_uint*)(gb + off + lane * 16),
                                             (lds_uint*)(lb + off), 16, 0, 0);
    }
    if (row0 + 64 <= n) {
        const float4* g4 = (const float4*)(X + (size_t)row0 * K);
        for (int i = t; i < 64 * (K / 4); i += 256) {
            float4 v = g4[i];
            int r = i / (K / 4), k0 = (i % (K / 4)) * 4;
            *(float4*)&Xs[r * KP + k0] = v;
        }
    } else {
        for (int i = t; i < 64 * K; i += 256) {
            int r = i / K, k = i % K;
            Xs[r * KP + k] = (row0 + r < n) ? X[(size_t)(row0 + r) * K + k] : 0.0f;
        }
    }
    __syncthreads();

    const int tx = t & 15;
    const int ty = t >> 4;
    float acc[4][4] = {{0.f}};
#pragma unroll 2
    for (int k0 = 0; k0 < K; k0 += 4) {
        float4 a0 = *(const float4*)&Xs[(4 * ty + 0) * KP + k0];
        float4 a1 = *(const float4*)&Xs[(4 * ty + 1) * KP + k0];
        float4 a2 = *(const float4*)&Xs[(4 * ty + 2) * KP + k0];
        float4 a3 = *(const float4*)&Xs[(4 * ty + 3) * KP + k0];
        float4 b0 = *(const float4*)&Ws[(k0 + 0) * 64 + 4 * tx];
        float4 b1 = *(const float4*)&Ws[(k0 + 1) * 64 + 4 * tx];
        float4 b2 = *(const float4*)&Ws[(k0 + 2) * 64 + 4 * tx];
        float4 b3 = *(const float4*)&Ws[(k0 + 3) * 64 + 4 * tx];
        const float* ap[4] = {(const float*)&a0, (const float*)&a1,
                              (const float*)&a2, (const float*)&a3};
        const float* bp[4] = {(const float*)&b0, (const float*)&b1,
                              (const float*)&b2, (const float*)&b3};
#pragma unroll
        for (int r = 0; r < 4; ++r)
#pragma unroll
            for (int kk = 0; kk < 4; ++kk) {
                float av = ap[r][kk];
#pragma unroll
                for (int c = 0; c < 4; ++c)
                    acc[r][c] = fmaf(av, bp[kk][c], acc[r][c]);
            }
    }
#pragma unroll
    for (int r = 0; r < 4; ++r) {
        int row = row0 + 4 * ty + r;
        if (row < n) {
            __half2 p01 = __floats2half2_rn(acc[r][0], acc[r][1]);
            __half2 p23 = __floats2half2_rn(acc[r][2], acc[r][3]);
            float2 st;
            ((__half2*)&st)[0] = p01;
            ((__half2*)&st)[1] = p23;
            *(float2*)&outh[(size_t)row * 64 + 4 * tx] = st;
        }
    }
}

// ================= K2a: exclusive scan of each bucket-row of S; T[b] = row total ====
__global__ __launch_bounds__(256) void scan_rows_kernel(
    int* __restrict__ S, int* __restrict__ T, int nb) {
    __shared__ int wsum[4];
    const int b = blockIdx.x, t = threadIdx.x;
    int v = (t < nb) ? S[(size_t)b * nb + t] : 0;
    int incl = blockScanIncl256(v, wsum);
    if (t < nb) S[(size_t)b * nb + t] = incl - v;
    if (t == 0) T[b] = wsum[3];
}

// ================= K2b: bucket scatter (redundant in-block T scan) ===========
__global__ __launch_bounds__(256) void scatter_kernel(
    const int* __restrict__ src, const int* __restrict__ dst, int E, int ePer,
    const int* __restrict__ S, const int* __restrict__ T,
    unsigned* __restrict__ ebuf, int nb) {
    __shared__ int arr[256];
    __shared__ int wsum[4];
    const int b = blockIdx.x, t = threadIdx.x;
    int tv = (t < nb) ? T[t] : 0;
    int tincl = blockScanIncl256(tv, wsum);
    int texcl = tincl - tv;
    if (t < nb) arr[t] = S[(size_t)t * nb + b] + texcl;
    __syncthreads();
    int beg = b * ePer, end = min(E, beg + ePer);
    for (int e = beg + t; e < end; e += 256) {
        int d = dst[e];
        int s = src[e];
        int pos = atomicAdd(&arr[d >> 8], 1);            // LDS atomic
        ebuf[pos] = ((unsigned)s << 8) | (unsigned)(d & 255);
    }
}

// ================= K2c: per-bucket CSR finalize (redundant in-block T scan) ==
__global__ __launch_bounds__(256) void build_kernel(
    const unsigned* __restrict__ ebuf, const int* __restrict__ T,
    int* __restrict__ row_ptr, float* __restrict__ dinv,
    int* __restrict__ esrc, int n, int nb) {
    __shared__ int arr[256];
    __shared__ int texcl_s[256];
    __shared__ int wsum[4];
    const int b = blockIdx.x, t = threadIdx.x;
    const int node0 = b << 8;

    int tv = (t < nb) ? T[t] : 0;
    int tincl = blockScanIncl256(tv, wsum);
    texcl_s[t] = tincl - tv;
    __syncthreads();
    const int ebeg = texcl_s[b];
    const int eend = (b + 1 < nb) ? texcl_s[b + 1] : wsum[3];

    arr[t] = 0;
    __syncthreads();
    for (int e = ebeg + t; e < eend; e += 256)
        atomicAdd(&arr[ebuf[e] & 255], 1);
    __syncthreads();
    int deg = arr[t];
    int incl = blockScanIncl256(deg, wsum);
    int excl = incl - deg;
    __syncthreads();
    arr[t] = ebeg + excl;   // cursor
    int v = node0 + t;
    if (v < n) {
        row_ptr[v + 1] = ebeg + incl;
        dinv[v] = rsqrtf(1.0f + (float)deg);
        if (v == 0) row_ptr[0] = 0;
    }
    __syncthreads();
    for (int e = ebeg + t; e < eend; e += 256) {
        unsigned p = ebuf[e];
        int pos = atomicAdd(&arr[p & 255], 1);           // LDS atomic
        esrc[pos] = (int)(p >> 8);
    }
}

// ================= K3: aggregate layer1 + gemm2 (fused) =================
// 4-lane group per node; unroll 4 edges (8 float4 loads in flight per group).
__global__ __launch_bounds__(256) void agg1_gemm2_kernel(
    const __half* __restrict__ g1, const int* __restrict__ row_ptr,
    const int* __restrict__ esrc, const float* __restrict__ dinv,
    const float* __restrict__ b1, const float* __restrict__ W2,
    __half* __restrict__ g2, int n) {
    __shared__ float Bt[64][68];
    __shared__ float Ws2[64 * 64];
    const int t = threadIdx.x, lane = t & 63, wav = t >> 6;

    {
        const char* gb = (const char*)W2;
        char* lb = (char*)Ws2;
        for (int off = wav * 1024; off < 64 * 64 * 4; off += 4096)
            __builtin_amdgcn_global_load_lds((glob_uint*)(gb + off + lane * 16),
                                             (lds_uint*)(lb + off), 16, 0, 0);
    }

    const int g = t >> 2;
    const int c = t & 3;
    const int row0 = blockIdx.x * 64;
    const int v = row0 + g;
    const float4* __restrict__ hs4 = (const float4*)g1;

    if (v < n) {
        float acc[16];
        float dv0 = dinv[v];
        {
            size_t rb = (size_t)v * 8 + 2 * c;
            float4 r0 = hs4[rb], r1 = hs4[rb + 1];
            const __half2* h0 = (const __half2*)&r0;
            const __half2* h1 = (const __half2*)&r1;
#pragma unroll
            for (int q = 0; q < 4; ++q) {
                float2 f0 = __half22float2(h0[q]);
                float2 f1 = __half22float2(h1[q]);
                acc[2 * q] = f0.x * dv0;     acc[2 * q + 1] = f0.y * dv0;
                acc[8 + 2 * q] = f1.x * dv0; acc[9 + 2 * q] = f1.y * dv0;
            }
        }
        const int beg = row_ptr[v], end = row_ptr[v + 1];
        int j = beg;
        for (; j + 4 <= end; j += 4) {
            int s0 = esrc[j], s1 = esrc[j + 1], s2 = esrc[j + 2], s3 = esrc[j + 3];
            float d0 = dinv[s0], d1 = dinv[s1], d2 = dinv[s2], d3 = dinv[s3];
            size_t rb0 = (size_t)s0 * 8 + 2 * c, rb1 = (size_t)s1 * 8 + 2 * c;
            size_t rb2 = (size_t)s2 * 8 + 2 * c, rb3 = (size_t)s3 * 8 + 2 * c;
            float4 a0 = hs4[rb0], a1 = hs4[rb0 + 1];
            float4 b0 = hs4[rb1], b1v = hs4[rb1 + 1];
            float4 c0 = hs4[rb2], c1 = hs4[rb2 + 1];
            float4 e0 = hs4[rb3], e1 = hs4[rb3 + 1];
            const __half2 *pa0 = (const __half2*)&a0, *pa1 = (const __half2*)&a1;
            const __half2 *pb0 = (const __half2*)&b0, *pb1 = (const __half2*)&b1v;
            const __half2 *pc0 = (const __half2*)&c0, *pc1 = (const __half2*)&c1;
            const __half2 *pe0 = (const __half2*)&e0, *pe1 = (const __half2*)&e1;
#pragma unroll
            for (int q = 0; q < 4; ++q) {
                float2 f;
                f = __half22float2(pa0[q]);
                acc[2 * q] = fmaf(f.x, d0, acc[2 * q]);
                acc[2 * q + 1] = fmaf(f.y, d0, acc[2 * q + 1]);
                f = __half22float2(pa1[q]);
                acc[8 + 2 * q] = fmaf(f.x, d0, acc[8 + 2 * q]);
                acc[9 + 2 * q] = fmaf(f.y, d0, acc[9 + 2 * q]);
                f = __half22float2(pb0[q]);
                acc[2 * q] = fmaf(f.x, d1, acc[2 * q]);
                acc[2 * q + 1] = fmaf(f.y, d1, acc[2 * q + 1]);
                f = __half22float2(pb1[q]);
                acc[8 + 2 * q] = fmaf(f.x, d1, acc[8 + 2 * q]);
                acc[9 + 2 * q] = fmaf(f.y, d1, acc[9 + 2 * q]);
                f = __half22float2(pc0[q]);
                acc[2 * q] = fmaf(f.x, d2, acc[2 * q]);
                acc[2 * q + 1] = fmaf(f.y, d2, acc[2 * q + 1]);
                f = __half22float2(pc1[q]);
                acc[8 + 2 * q] = fmaf(f.x, d2, acc[8 + 2 * q]);
                acc[9 + 2 * q] = fmaf(f.y, d2, acc[9 + 2 * q]);
                f = __half22float2(pe0[q]);
                acc[2 * q] = fmaf(f.x, d3, acc[2 * q]);
                acc[2 * q + 1] = fmaf(f.y, d3, acc[2 * q + 1]);
                f = __half22float2(pe1[q]);
                acc[8 + 2 * q] = fmaf(f.x, d3, acc[8 + 2 * q]);
                acc[9 + 2 * q] = fmaf(f.y, d3, acc[9 + 2 * q]);
            }
        }
        for (; j < end; ++j) {
            int s0 = esrc[j];
            float d0 = dinv[s0];
            size_t rb0 = (size_t)s0 * 8 + 2 * c;
            float4 a0 = hs4[rb0], a1 = hs4[rb0 + 1];
            const __half2 *pa0 = (const __half2*)&a0, *pa1 = (const __half2*)&a1;
#pragma unroll
            for (int q = 0; q < 4; ++q) {
                float2 f;
                f = __half22float2(pa0[q]);
                acc[2 * q] = fmaf(f.x, d0, acc[2 * q]);
                acc[2 * q + 1] = fmaf(f.y, d0, acc[2 * q + 1]);
                f = __half22float2(pa1[q]);
                acc[8 + 2 * q] = fmaf(f.x, d0, acc[8 + 2 * q]);
                acc[9 + 2 * q] = fmaf(f.y, d0, acc[9 + 2 * q]);
            }
        }
        const float* bb = b1 + c * 16;
#pragma unroll
        for (int u = 0; u < 4; ++u) {
            float4 w;
            w.x = fmaxf(fmaf(acc[4 * u + 0], dv0, bb[4 * u + 0]), 0.f);
            w.y = fmaxf(fmaf(acc[4 * u + 1], dv0, bb[4 * u + 1]), 0.f);
            w.z = fmaxf(fmaf(acc[4 * u + 2], dv0, bb[4 * u + 2]), 0.f);
            w.w = fmaxf(fmaf(acc[4 * u + 3], dv0, bb[4 * u + 3]), 0.f);
            *(float4*)&Bt[g][c * 16 + 4 * u] = w;
        }
    } else {
#pragma unroll
        for (int u = 0; u < 4; ++u)
            *(float4*)&Bt[g][c * 16 + 4 * u] = make_float4(0.f, 0.f, 0.f, 0.f);
    }
    __syncthreads();

    const int tx = t & 15;
    const int ty = t >> 4;
    float a2[4][4] = {{0.f}};
#pragma unroll 2
    for (int k0 = 0; k0 < 64; k0 += 4) {
        float4 x0 = *(const float4*)&Bt[4 * ty + 0][k0];
        float4 x1 = *(const float4*)&Bt[4 * ty + 1][k0];
        float4 x2 = *(const float4*)&Bt[4 * ty + 2][k0];
        float4 x3 = *(const float4*)&Bt[4 * ty + 3][k0];
        float4 w0 = *(const float4*)&Ws2[(k0 + 0) * 64 + 4 * tx];
        float4 w1 = *(const float4*)&Ws2[(k0 + 1) * 64 + 4 * tx];
        float4 w2 = *(const float4*)&Ws2[(k0 + 2) * 64 + 4 * tx];
        float4 w3 = *(const float4*)&Ws2[(k0 + 3) * 64 + 4 * tx];
        const float* xp[4] = {(const float*)&x0, (const float*)&x1,
                              (const float*)&x2, (const float*)&x3};
        const float* wp[4] = {(const float*)&w0, (const float*)&w1,
                              (const float*)&w2, (const float*)&w3};
#pragma unroll
        for (int r = 0; r < 4; ++r)
#pragma unroll
            for (int kk = 0; kk < 4; ++kk) {
                float av = xp[r][kk];
#pragma unroll
                for (int cc = 0; cc < 4; ++cc)
                    a2[r][cc] = fmaf(av, wp[kk][cc], a2[r][cc]);
            }
    }
#pragma unroll
    for (int r = 0; r < 4; ++r) {
        int row = row0 + 4 * ty + r;
        if (row < n) {
            float dv = dinv[row];
            __half2 p01 = __floats2half2_rn(a2[r][0] * dv, a2[r][1] * dv);
            __half2 p23 = __floats2half2_rn(a2[r][2] * dv, a2[r][3] * dv);
            float2 st;
            ((__half2*)&st)[0] = p01;
            ((__half2*)&st)[1] = p23;
            *(float2*)&g2[(size_t)row * 64 + 4 * tx] = st;
        }
    }
}

// ================= K4: aggregate layer2 -> d_out =================
__global__ __launch_bounds__(256) void aggregate2_kernel(
    const __half* __restrict__ hs,
    const int* __restrict__ row_ptr,
    const int* __restrict__ esrc,
    const float* __restrict__ dinv,
    const float* __restrict__ bias,
    float* __restrict__ out, int n) {
    const int v = blockIdx.x * 32 + (threadIdx.x >> 3);
    if (v >= n) return;
    const int c8 = threadIdx.x & 7;
    const float4* __restrict__ hs4 = (const float4*)hs;

    const int beg = row_ptr[v];
    const int end = row_ptr[v + 1];

    float acc[8];
    {
        float4 raw = hs4[(size_t)v * 8 + c8];
        const __half2* hp = (const __half2*)&raw;
#pragma unroll
        for (int q = 0; q < 4; ++q) {
            float2 f = __half22float2(hp[q]);
            acc[2 * q] = f.x; acc[2 * q + 1] = f.y;
        }
    }

    int j = beg;
    for (; j + 4 <= end; j += 4) {
        int s0 = esrc[j], s1 = esrc[j + 1], s2 = esrc[j + 2], s3 = esrc[j + 3];
        float4 r0 = hs4[(size_t)s0 * 8 + c8];
        float4 r1 = hs4[(size_t)s1 * 8 + c8];
        float4 r2 = hs4[(size_t)s2 * 8 + c8];
        float4 r3 = hs4[(size_t)s3 * 8 + c8];
        const __half2* h0 = (const __half2*)&r0;
        const __half2* h1 = (const __half2*)&r1;
        const __half2* h2 = (const __half2*)&r2;
        const __half2* h3 = (const __half2*)&r3;
#pragma unroll
        for (int q = 0; q < 4; ++q) {
            float2 f0 = __half22float2(h0[q]);
            float2 f1 = __half22float2(h1[q]);
            float2 f2 = __half22float2(h2[q]);
            float2 f3 = __half22float2(h3[q]);
            acc[2 * q]     += (f0.x + f1.x) + (f2.x + f3.x);
            acc[2 * q + 1] += (f0.y + f1.y) + (f2.y + f3.y);
        }
    }
    for (; j < end; ++j) {
        int s0 = esrc[j];
        float4 r0 = hs4[(size_t)s0 * 8 + c8];
        const __half2* h0 = (const __half2*)&r0;
#pragma unroll
        for (int q = 0; q < 4; ++q) {
            float2 f0 = __half22float2(h0[q]);
            acc[2 * q] += f0.x;
            acc[2 * q + 1] += f0.y;
        }
    }

    float dv = dinv[v];
    float4 b0 = *(const float4*)(bias + c8 * 8);
    float4 b1v = *(const float4*)(bias + c8 * 8 + 4);
    float4 o0, o1;
    o0.x = fmaf(acc[0], dv, b0.x); o0.y = fmaf(acc[1], dv, b0.y);
    o0.z = fmaf(acc[2], dv, b0.z); o0.w = fmaf(acc[3], dv, b0.w);
    o1.x = fmaf(acc[4], dv, b1v.x); o1.y = fmaf(acc[5], dv, b1v.y);
    o1.z = fmaf(acc[6], dv, b1v.z); o1.w = fmaf(acc[7], dv, b1v.w);
    float4* op = (float4*)(out + (size_t)v * 64 + c8 * 8);
    op[0] = o0;
    op[1] = o1;
}

extern "C" void kernel_launch(void* const* d_in, const int* in_sizes, int n_in,
                              void* d_out, int out_size, void* d_ws, size_t ws_size,
                              hipStream_t stream) {
    const float* x  = (const float*)d_in[0];
    const int*   ei = (const int*)d_in[1];
    const float* W1 = (const float*)d_in[2];
    const float* b1 = (const float*)d_in[3];
    const float* W2 = (const float*)d_in[4];
    const float* b2 = (const float*)d_in[5];
    float* out = (float*)d_out;

    const int C_IN = 128;
    const int n = in_sizes[0] / C_IN;   // 50000 (<= 65536 required)
    const int E = in_sizes[1] / 2;      // 800000
    const int* src = ei;
    const int* dst = ei + E;

    const int nb = (n + 255) >> 8;              // 196 buckets (<= 256)
    const int ngb = (n + 63) / 64;              // gemm tile blocks
    const int ePer = (E + nb - 1) / nb;         // edges per hist/scatter chunk

    // Workspace: dinv | g1 | g2 | row_ptr | S | T | ebuf | esrc
    char* w = (char*)d_ws;
    float*    dinv    = (float*)w;    w += alignup((size_t)n * sizeof(float));
    __half*   g1      = (__half*)w;   w += alignup((size_t)n * C_HID * sizeof(__half));
    __half*   g2      = (__half*)w;   w += alignup((size_t)n * C_HID * sizeof(__half));
    int*      row_ptr = (int*)w;      w += alignup((size_t)(n + 1) * sizeof(int));
    int*      S       = (int*)w;      w += alignup((size_t)nb * nb * sizeof(int));
    int*      T       = (int*)w;      w += alignup((size_t)(nb + 1) * sizeof(int));
    unsigned* ebuf    = (unsigned*)w; w += alignup((size_t)E * sizeof(unsigned));
    int*      esrc    = (int*)w;

    // K1: gemm1 || hist
    gemm1_hist_kernel<128><<<nb + ngb, 256, 0, stream>>>(
        x, W1, dst, g1, S, n, E, ePer, nb);

    // K2: CSR build (launch boundaries as barriers; T scanned redundantly in-block)
    scan_rows_kernel<<<nb, 256, 0, stream>>>(S, T, nb);
    scatter_kernel<<<nb, 256, 0, stream>>>(src, dst, E, ePer, S, T, ebuf, nb);
    build_kernel<<<nb, 256, 0, stream>>>(ebuf, T, row_ptr, dinv, esrc, n, nb);

    // K3: aggregate layer1 + gemm2 fused
    agg1_gemm2_kernel<<<ngb, 256, 0, stream>>>(
        g1, row_ptr, esrc, dinv, b1, W2, g2, n);

    // K4: aggregate layer2 -> out
    aggregate2_kernel<<<(n + 31) / 32, 256, 0, stream>>>(
        g2, row_ptr, esrc, dinv, b2, out, n);
}